// Round 1
// baseline (1345.923 us; speedup 1.0000x reference)
//
#include <hip/hip_runtime.h>
#include <stdint.h>

// Problem constants (GRU_12764642803875)
#define Bsz 8
#define Ssz 1024
#define STATEsz 1024
#define Hsz 8
#define Dsz 128

typedef float  f32x4  __attribute__((ext_vector_type(4)));
typedef int    i32x4  __attribute__((ext_vector_type(4)));
typedef __bf16 bf16x8 __attribute__((ext_vector_type(8)));

__device__ __forceinline__ unsigned short f2bf(float f){
  unsigned int u = __float_as_uint(f);
  u = u + 0x7FFFu + ((u >> 16) & 1u);   // round-to-nearest-even
  return (unsigned short)(u >> 16);
}
__device__ __forceinline__ float bf2f(unsigned short s){
  return __uint_as_float(((unsigned int)s) << 16);
}
__device__ __forceinline__ float sigmoid_(float x){ return 1.f/(1.f+__expf(-x)); }
// tanh via sigmoid form: no inf/inf NaN at large |x|
__device__ __forceinline__ float tanh_(float x){ return 2.f/(1.f+__expf(-2.f*x)) - 1.f; }

// ---------------- fp32 -> bf16 cast, 4-wide ----------------
__global__ void k_cast_bf16(const float* __restrict__ in, unsigned short* __restrict__ out, int n4){
  int i = blockIdx.x*blockDim.x + threadIdx.x;
  if (i >= n4) return;
  f32x4 v = ((const f32x4*)in)[i];
  ushort4 o;
  o.x = f2bf(v[0]); o.y = f2bf(v[1]); o.z = f2bf(v[2]); o.w = f2bf(v[3]);
  ((ushort4*)out)[i] = o;
}

// ---------------- fp32 [R][C] -> bf16 [C][R] transpose ----------------
__global__ void k_transpose_bf16(const float* __restrict__ in, unsigned short* __restrict__ out, int R, int C){
  __shared__ float tile[32][33];
  int c0 = blockIdx.x*32, r0 = blockIdx.y*32;
  int tx = threadIdx.x, ty = threadIdx.y;   // block (32,8)
  #pragma unroll
  for (int i=0;i<4;++i) tile[ty+8*i][tx] = in[(size_t)(r0+ty+8*i)*C + c0+tx];
  __syncthreads();
  #pragma unroll
  for (int i=0;i<4;++i) out[(size_t)(c0+ty+8*i)*R + r0+tx] = f2bf(tile[tx][ty+8*i]);
}

// ---------------- bf16 MFMA GEMM: C[M,N] = A[M,K] @ Bt[N,K]^T (+bias) ----------------
// 128x128 tile, BK=32, 256 threads = 4 waves (2x2 of 64x64), 16x16x32 MFMA.
// LDS rows padded to 40 elems (80B) -> conflict-free ds_read_b128 frag reads.
template<bool BF16_OUT, bool BIAS>
__global__ __launch_bounds__(256) void k_gemm(
    const unsigned short* __restrict__ A, const unsigned short* __restrict__ Bt,
    const float* __restrict__ bias, unsigned short* __restrict__ Cb, float* __restrict__ Cf,
    int M, int N, int K){
  __shared__ unsigned short As[128][40];
  __shared__ unsigned short Bs[128][40];
  int t = threadIdx.x;
  int l = t & 63, w = t >> 6, wm = w >> 1, wn = w & 1;
  int m0 = blockIdx.y*128, n0 = blockIdx.x*128;
  f32x4 acc[4][4];
  #pragma unroll
  for(int a=0;a<4;++a)
    #pragma unroll
    for(int b=0;b<4;++b){ acc[a][b][0]=0.f; acc[a][b][1]=0.f; acc[a][b][2]=0.f; acc[a][b][3]=0.f; }
  int lr = l & 15, lk = (l >> 4)*8;
  for(int k0=0;k0<K;k0+=32){
    #pragma unroll
    for(int it=0; it<2; ++it){              // stage 128x32 bf16 for A and Bt (reg-staged, padded LDS)
      int idx = t + 256*it, r = idx>>2, q = idx&3;
      i32x4 av = *(const i32x4*)(A  + (size_t)(m0+r)*K + k0 + q*8);
      i32x4 bv = *(const i32x4*)(Bt + (size_t)(n0+r)*K + k0 + q*8);
      *(i32x4*)(&As[r][q*8]) = av;
      *(i32x4*)(&Bs[r][q*8]) = bv;
    }
    __syncthreads();
    bf16x8 af[4], bfv[4];
    #pragma unroll
    for(int mi=0;mi<4;++mi) af[mi]  = *(const bf16x8*)(&As[wm*64+mi*16+lr][lk]);
    #pragma unroll
    for(int ni=0;ni<4;++ni) bfv[ni] = *(const bf16x8*)(&Bs[wn*64+ni*16+lr][lk]);
    #pragma unroll
    for(int mi=0;mi<4;++mi)
      #pragma unroll
      for(int ni=0;ni<4;++ni)
        acc[mi][ni] = __builtin_amdgcn_mfma_f32_16x16x32_bf16(af[mi], bfv[ni], acc[mi][ni], 0,0,0);
    __syncthreads();
  }
  // C/D layout: col = lane&15, row = (lane>>4)*4 + j  [m89-verified]
  int cr0 = (l>>4)*4;
  #pragma unroll
  for(int mi=0;mi<4;++mi){
    #pragma unroll
    for(int ni=0;ni<4;++ni){
      int col = n0 + wn*64 + ni*16 + lr;
      float bv = BIAS ? bias[col] : 0.f;
      #pragma unroll
      for(int j=0;j<4;++j){
        int row = m0 + wm*64 + mi*16 + cr0 + j;
        float v = acc[mi][ni][j] + bv;
        if (BF16_OUT) Cb[(size_t)row*N + col] = f2bf(v);
        else          Cf[(size_t)row*N + col] = v;
      }
    }
  }
}

// ---------------- serial recurrence: 64 blocks = (b,h), 512 threads ----------------
// thread t: e = t&127 (output elem), s = t>>7 (d-slice, wave-uniform -> LDS broadcast reads)
// weights fp32 in VGPRs (96/thread); 4 barriers/step; z/f/r prefetched 1 step ahead.
__global__ __launch_bounds__(512) void k_rnn(
    const unsigned short* __restrict__ proj,   // [B*S][3072] bf16: [z|f|r] each 1024
    const float* __restrict__ h0,
    const float* __restrict__ Wst, const float* __restrict__ Wfg, const float* __restrict__ Wrs,
    unsigned short* __restrict__ hs, float* __restrict__ hT){
  int b = blockIdx.x >> 3, h = blockIdx.x & 7;
  int t = threadIdx.x, e = t & 127, s = t >> 7;
  __shared__ float h_l[128], rh_l[128], f_l[128];
  __shared__ float parts[3][4][128];
  float wr[32], wf[32], wsw[32];
  {
    const float* br  = Wrs + h*16384 + (32*s)*128 + e;
    const float* bff = Wfg + h*16384 + (32*s)*128 + e;
    const float* bss = Wst + h*16384 + (32*s)*128 + e;
    #pragma unroll
    for(int i=0;i<32;++i){ wr[i] = br[i*128]; wf[i] = bff[i*128]; wsw[i] = bss[i*128]; }
  }
  if (t < 128) h_l[e] = h0[b*STATEsz + h*Dsz + e];
  const unsigned short* pb = proj + (size_t)b*Ssz*3072 + h*Dsz + e;
  float cz=0.f, cf=0.f, cr=0.f, nz=0.f, nf=0.f, nr=0.f;
  if (t < 128){ cz = bf2f(pb[0]); cf = bf2f(pb[1024]); cr = bf2f(pb[2048]); }
  __syncthreads();
  for(int st=0; st<Ssz; ++st){
    if (t < 128 && st+1 < Ssz){            // prefetch next step's z/f/r
      const unsigned short* p = pb + (size_t)(st+1)*3072;
      nz = bf2f(p[0]); nf = bf2f(p[1024]); nr = bf2f(p[2048]);
    }
    // phase 1: partial dots for r and f gates (h broadcast from LDS)
    float pr = 0.f, pf = 0.f;
    const f32x4* h4 = (const f32x4*)&h_l[32*s];
    #pragma unroll
    for(int i=0;i<8;++i){
      f32x4 hv = h4[i];
      #pragma unroll
      for(int j=0;j<4;++j){ pr += hv[j]*wr[4*i+j]; pf += hv[j]*wf[4*i+j]; }
    }
    parts[0][s][e] = pr; parts[1][s][e] = pf;
    __syncthreads();
    if (t < 128){
      float rs = cr + parts[0][0][e] + parts[0][1][e] + parts[0][2][e] + parts[0][3][e];
      float fs = cf + parts[1][0][e] + parts[1][1][e] + parts[1][2][e] + parts[1][3][e];
      float r  = sigmoid_(rs);
      f_l[e]   = sigmoid_(fs);
      rh_l[e]  = r * h_l[e];
    }
    __syncthreads();
    // phase 2: partial dot for candidate (rh broadcast from LDS)
    float pc = 0.f;
    const f32x4* rh4 = (const f32x4*)&rh_l[32*s];
    #pragma unroll
    for(int i=0;i<8;++i){
      f32x4 rv = rh4[i];
      #pragma unroll
      for(int j=0;j<4;++j) pc += rv[j]*wsw[4*i+j];
    }
    parts[2][s][e] = pc;
    __syncthreads();
    if (t < 128){
      float cs = cz + parts[2][0][e]+parts[2][1][e]+parts[2][2][e]+parts[2][3][e];
      float c  = tanh_(cs);
      float f  = f_l[e];
      float hn = f*h_l[e] + (1.f - f)*c;
      h_l[e] = hn;
      hs[((size_t)b*Ssz + st)*STATEsz + h*Dsz + e] = f2bf(hn);
      cz = nz; cf = nf; cr = nr;
    }
    __syncthreads();
  }
  if (t < 128) hT[b*STATEsz + h*Dsz + e] = h_l[e];
}

// ---------------- launch ----------------
// ws layout (bytes):                      size
//   xbf   @ 0          bf16[8192*1024]    16,777,216
//   WiT   @ 16777216   bf16[3072*1024]     6,291,456
//   WoT   @ 23068672   bf16[1024*1024]     2,097,152
//   proj  @ 25165824   bf16[8192*3072]    50,331,648
//   hs    @ 75497472   bf16[8192*1024]    16,777,216
// total 92,274,688 B (assumes ws_size >= 92.3 MB)
extern "C" void kernel_launch(void* const* d_in, const int* in_sizes, int n_in,
                              void* d_out, int out_size, void* d_ws, size_t ws_size,
                              hipStream_t stream){
  const float* x   = (const float*)d_in[0];
  const float* h0  = (const float*)d_in[1];
  const float* Wi  = (const float*)d_in[2];
  const float* bi  = (const float*)d_in[3];
  const float* Wst = (const float*)d_in[4];
  const float* Wfg = (const float*)d_in[5];
  const float* Wrs = (const float*)d_in[6];
  const float* Wo  = (const float*)d_in[7];
  float* out = (float*)d_out;
  float* hT  = out + (size_t)Bsz*Ssz*1024;

  char* ws = (char*)d_ws;
  unsigned short* xbf  = (unsigned short*)(ws);
  unsigned short* WiT  = (unsigned short*)(ws + 16777216);
  unsigned short* WoT  = (unsigned short*)(ws + 23068672);
  unsigned short* proj = (unsigned short*)(ws + 25165824);
  unsigned short* hsb  = (unsigned short*)(ws + 75497472);

  k_cast_bf16<<<dim3(8192), dim3(256), 0, stream>>>(x, xbf, 2097152);
  k_transpose_bf16<<<dim3(3072/32, 1024/32), dim3(32,8), 0, stream>>>(Wi, WiT, 1024, 3072);
  k_transpose_bf16<<<dim3(1024/32, 1024/32), dim3(32,8), 0, stream>>>(Wo, WoT, 1024, 1024);
  k_gemm<true,true><<<dim3(3072/128, 8192/128), dim3(256), 0, stream>>>(
      xbf, WiT, bi, proj, nullptr, 8192, 3072, 1024);
  k_rnn<<<dim3(64), dim3(512), 0, stream>>>(proj, h0, Wst, Wfg, Wrs, hsb, hT);
  k_gemm<false,false><<<dim3(1024/128, 8192/128), dim3(256), 0, stream>>>(
      hsb, WoT, nullptr, nullptr, out, 8192, 1024, 1024);
}